// Round 4
// baseline (588.804 us; speedup 1.0000x reference)
//
#include <hip/hip_runtime.h>
#include <hip/hip_bf16.h>
#include <stdint.h>

#define SEQ   2048
#define DIM   4096
#define NH    32
#define NKV   8
#define HD    128
#define NREP  4
#define QKVN  6144   /* 4096 q | 1024 k | 1024 v */
#define KOFF  4096
#define VOFF  5120

typedef __bf16 bf16;
typedef __attribute__((ext_vector_type(8))) __bf16 bf16x8;
typedef __attribute__((ext_vector_type(4))) __bf16 bf16x4;
typedef __attribute__((ext_vector_type(4))) float  f32x4;
typedef __attribute__((address_space(1))) void as1_void;
typedef __attribute__((address_space(3))) void as3_void;

__device__ __forceinline__ void async_copy16(void* lds, const void* g) {
  // LDS dest is wave-uniform base + lane*16; global side may be lane-permuted.
  __builtin_amdgcn_global_load_lds((as1_void*)(void*)g, (as3_void*)lds, 16, 0, 0);
}

__device__ __forceinline__ uint32_t pack2bf(float a, float b) {
  union { bf16 h; uint16_t u; } ca, cb;
  ca.h = (bf16)a; cb.h = (bf16)b;
  return (uint32_t)ca.u | ((uint32_t)cb.u << 16);
}

__device__ __forceinline__ void block_barrier() {
  asm volatile("" ::: "memory");
  __builtin_amdgcn_s_barrier();
  asm volatile("" ::: "memory");
}

// ---------------- elementwise fp32 -> bf16 cast (x) ----------------
__global__ __launch_bounds__(256) void cast_x_kernel(const float* __restrict__ src,
                                                     bf16* __restrict__ dst) {
  size_t i = ((size_t)blockIdx.x * 256 + threadIdx.x) * 4;
  const float4 v = *(const float4*)(src + i);
  bf16x4 o;
  o[0] = (bf16)v.x; o[1] = (bf16)v.y; o[2] = (bf16)v.z; o[3] = (bf16)v.w;
  *(bf16x4*)(dst + i) = o;
}

// ---------------- tiled transpose-cast: 64x64, float4 loads, bf16x4 stores ----------------
__global__ __launch_bounds__(256) void transpose_cast_kernel(const float* __restrict__ src,
                                                             bf16* __restrict__ dst,
                                                             int R, int C) {
  __shared__ float tile[64][65];
  const int c0 = blockIdx.x * 64, r0 = blockIdx.y * 64;
  const int tx = threadIdx.x & 15, ty = threadIdx.x >> 4;   // 16 x 16
#pragma unroll
  for (int p = 0; p < 4; ++p) {
    float4 v = *(const float4*)&src[(size_t)(r0 + ty + p*16) * C + c0 + tx*4];
    tile[ty + p*16][tx*4+0] = v.x;
    tile[ty + p*16][tx*4+1] = v.y;
    tile[ty + p*16][tx*4+2] = v.z;
    tile[ty + p*16][tx*4+3] = v.w;
  }
  __syncthreads();
  const int k = threadIdx.x & 15;   // dst col quad
  const int g = threadIdx.x >> 4;   // dst row group
#pragma unroll
  for (int p = 0; p < 4; ++p) {
    int X = g + 16*p;               // src col = dst row
    bf16x4 o;
    o[0] = (bf16)tile[4*k+0][X];
    o[1] = (bf16)tile[4*k+1][X];
    o[2] = (bf16)tile[4*k+2][X];
    o[3] = (bf16)tile[4*k+3][X];
    *(bf16x4*)&dst[(size_t)(c0 + X) * R + r0 + 4*k] = o;
  }
}

// ---------------- GEMM v6: 256xBN, BK=64, 8 waves, TRUE 8-phase (4 phases/tile) ----------
// C(MxN) = A(MxK) * Bt(NxK)^T, bf16 in, fp32 acc. Grid = exactly 256 blocks (1/CU).
// LDS layout (unchanged from v5, 0 conflicts, coalesced staging):
//   per tile [row][8 slots x 16B], phys slot sl holds k-chunk (sl ^ (row&7)).
// Schedule per K-tile t (phases P0..P3 = (ks,qm) pairs), per the m201 template:
//   P0: ds_read{b0,af} ; stage A(t+1) row-half0 ; bar ; lgkm0 ; MFMA ; bar
//   P1: ds_read{af}    ; stage A(t+1) row-half1 ; bar ; lgkm0 ; MFMA ; bar
//   P2: ds_read{b1,af} ; stage B(t+2) full      ; bar ; lgkm0 ; MFMA ; bar
//   P3: ds_read{af}    ;                          bar ; lgkm0 ; MFMA ; vmcnt(BCH) ; bar
// In-place A staging is safe: buffer nb's reads ended at (t-1).P3 (lgkm0 before trailing
// barrier). B triple-buffered: (t+2)%3 == (t-1)%3, last read at (t-1).P2. The single
// counted vmcnt(BCH) keeps only B(t+2) in flight and drains A(t+1)/B(t+1) (issued 2-5
// phases earlier) before tile t+1 reads them. vmcnt(0) only in the last two tiles.
template<int OUT_F32, int ROPE, int BN>
__global__ __launch_bounds__(512, 2) void gemm256_kernel(const bf16* __restrict__ A,
                                                         const bf16* __restrict__ Bt,
                                                         void* __restrict__ Cout,
                                                         int M, int N, int K,
                                                         const float* __restrict__ fr) {
  constexpr int BNF = BN / 64;            // B fragments per wave (wave owns BN/4 cols)
  constexpr int BCH = BN / 64;            // B tile chunks per thread (BN*8 / 512)
  constexpr int BBUF = BN * 128;          // one B buffer bytes
  __shared__ __align__(16) char ldsA[2 * 32768];
  __shared__ __align__(16) char ldsB[3 * BBUF];

  const int tid  = threadIdx.x;
  const int w    = tid >> 6, lane = tid & 63;
  const int lane16 = lane & 15, quad = lane >> 4;
  const int wm = w >> 2, wn = w & 3;               // 2(M) x 4(N) wave grid

  // XCD-aware block swizzle (grid is exactly 256 = 8*32 blocks): XCD k owns M-row k
  const int nwg = gridDim.x * gridDim.y;
  int bid = blockIdx.y * gridDim.x + blockIdx.x;
  bid = (bid & 7) * (nwg >> 3) + (bid >> 3);
  const int bx = bid % gridDim.x, by = bid / gridDim.x;
  const int bm = by * 256, bn = bx * BN;

  const int NT = K >> 6;

  // stage A row-half h of tile t: rows h*128..h*128+127 = 1024 chunks, 2/thread.
  // chunk c -> row = h*128 + (c>>3), phys slot = c&7, global k-chunk = (c&7)^(row&7).
  auto stageAh = [&](int buf, int t, int h) {
#pragma unroll
    for (int i = 0; i < 2; ++i) {
      int c = tid + (i << 9);
      int row = h*128 + (c >> 3), sl = c & 7;
      async_copy16(ldsA + buf*32768 + h*16384 + c*16,
                   A + (size_t)(bm + row) * K + t*64 + ((sl ^ (row & 7)) << 3));
    }
  };
  // stage full B tile (BN*8 chunks, BCH/thread)
  auto stageB = [&](int buf, int t) {
#pragma unroll
    for (int i = 0; i < BCH; ++i) {
      int c = tid + (i << 9);
      int col = c >> 3, sl = c & 7;
      async_copy16(ldsB + buf*BBUF + c*16,
                   Bt + (size_t)(bn + col) * K + t*64 + ((sl ^ (col & 7)) << 3));
    }
  };

  f32x4 acc[8][BNF] = {};

#define LD_A(DST, BUF, KS, QM)                                                        \
  do {                                                                                \
    _Pragma("unroll")                                                                 \
    for (int ii = 0; ii < 4; ++ii) {                                                  \
      int row_ = wm*128 + (QM)*64 + ii*16 + lane16;                                   \
      int S_ = ((KS)*4 + quad) ^ (lane16 & 7);                                        \
      (DST)[ii] = *(const bf16x8*)(ldsA + (BUF)*32768 + row_*128 + S_*16);            \
    }                                                                                 \
  } while (0)
#define LD_B(DST, BUF, KS)                                                            \
  do {                                                                                \
    _Pragma("unroll")                                                                 \
    for (int jj = 0; jj < BNF; ++jj) {                                                \
      int col_ = wn*(BN/4) + jj*16 + lane16;                                          \
      int S_ = ((KS)*4 + quad) ^ (lane16 & 7);                                        \
      (DST)[jj] = *(const bf16x8*)(ldsB + (BUF)*BBUF + col_*128 + S_*16);             \
    }                                                                                 \
  } while (0)
#define SYNC_MMA(AF, BF, QM)                                                          \
  do {                                                                                \
    block_barrier();                                                                  \
    asm volatile("s_waitcnt lgkmcnt(0)" ::: "memory");                                \
    __builtin_amdgcn_sched_barrier(0);                                                \
    __builtin_amdgcn_s_setprio(1);                                                    \
    _Pragma("unroll")                                                                 \
    for (int jj = 0; jj < BNF; ++jj)                                                  \
      _Pragma("unroll")                                                               \
      for (int ii = 0; ii < 4; ++ii)                                                  \
        acc[(QM)*4 + ii][jj] = __builtin_amdgcn_mfma_f32_16x16x32_bf16(               \
            (AF)[ii], (BF)[jj], acc[(QM)*4 + ii][jj], 0, 0, 0);                       \
    __builtin_amdgcn_s_setprio(0);                                                    \
  } while (0)

  // prologue: A(0) both halves, B(0), B(1). Keep only B(1) in flight.
  stageAh(0, 0, 0); stageAh(0, 0, 1); stageB(0, 0); stageB(1, 1);
  asm volatile("s_waitcnt vmcnt(%0)" :: "i"(BCH) : "memory");
  block_barrier();

  for (int t = 0; t < NT; ++t) {
    const int ca = t & 1, na = ca ^ 1;
    const int cbb = t % 3;
    bf16x8 af[4], b0[BNF], b1[BNF];

    // ---- P0: ks0, qm0 ----
    LD_B(b0, cbb, 0);
    LD_A(af, ca, 0, 0);
    if (t + 1 < NT) stageAh(na, t + 1, 0);
    SYNC_MMA(af, b0, 0);
    block_barrier();

    // ---- P1: ks0, qm1 ----
    LD_A(af, ca, 0, 1);
    if (t + 1 < NT) stageAh(na, t + 1, 1);
    SYNC_MMA(af, b0, 1);
    block_barrier();

    // ---- P2: ks1, qm0 ----
    LD_B(b1, cbb, 1);
    LD_A(af, ca, 1, 0);
    if (t + 2 < NT) stageB((t + 2) % 3, t + 2);
    SYNC_MMA(af, b1, 0);
    block_barrier();

    // ---- P3: ks1, qm1 ----
    LD_A(af, ca, 1, 1);
    SYNC_MMA(af, b1, 1);
    if (t + 2 < NT) asm volatile("s_waitcnt vmcnt(%0)" :: "i"(BCH) : "memory");
    else            asm volatile("s_waitcnt vmcnt(0)" ::: "memory");
    block_barrier();
  }

  // epilogue: C write (+ optional fused RoPE on cols < 5120)
#pragma unroll
  for (int i = 0; i < 8; ++i)
#pragma unroll
    for (int j = 0; j < BNF; ++j) {
      const int colb = bn + wn*(BN/4) + j*16;
      const bool do_rope = ROPE && colb < 5120;          // wave-uniform per j
      const int p2 = (colb + lane16) & 126;              // 2*p within head
#pragma unroll
      for (int r = 0; r < 4; ++r) {
        size_t row = (size_t)bm + wm*128 + i*16 + quad*4 + r;  // C/D: row=quad*4+reg
        size_t col = (size_t)colb + lane16;                    //      col=lane&15
        float v = acc[i][j][r];
        if (ROPE) {
          float vp = __shfl_xor(v, 1);                   // partner feature value
          if (do_rope) {
            float2 cd = *(const float2*)&fr[row*128 + p2];
            v = (lane16 & 1) ? (vp*cd.y + v*cd.x) : (v*cd.x - vp*cd.y);
          }
        }
        if (OUT_F32) ((float*)Cout)[row * N + col] = v;
        else         ((bf16*)Cout)[row * N + col] = (bf16)v;
      }
    }
#undef LD_A
#undef LD_B
#undef SYNC_MMA
}

// ---------------- transpose v slice of qkv -> vt[kv][d][t] ----------------
__global__ __launch_bounds__(256) void transpose_v_kernel(const bf16* __restrict__ qkv,
                                                          bf16* __restrict__ vt) {
  __shared__ bf16 tile[32][33];
  int tt = blockIdx.x * 32;
  int dd = blockIdx.y * 32;
  int kv = blockIdx.z;
  int tx = threadIdx.x & 31, ty = threadIdx.x >> 5;
  const bf16* src = qkv + VOFF + kv * HD;
#pragma unroll
  for (int j = 0; j < 4; ++j)
    tile[ty + j*8][tx] = src[(size_t)(tt + ty + j*8) * QKVN + dd + tx];
  __syncthreads();
  bf16* dst = vt + ((size_t)kv * HD + dd) * SEQ + tt;
#pragma unroll
  for (int j = 0; j < 4; ++j)
    dst[(size_t)(ty + j*8) * SEQ + tx] = tile[tx][ty + j*8];
}

// ---------------- flash attention v3 (unchanged) ----------------
__global__ __launch_bounds__(256, 3) void flash_attn_kernel(const bf16* __restrict__ qkv,
                                                            const bf16* __restrict__ vt,
                                                            bf16* __restrict__ out) {
  __shared__ __align__(16) bf16 Ks[4*96*32];    // [kk=4][kvrow=96][32]   24 KB
  __shared__ __align__(16) bf16 Vts[3*128*32];  // [kk2=3][d=128][32kv]   24 KB
  const int b  = blockIdx.x;                    // 1D, qt-descending for balance
  const int qt = 31 - (b >> 5);
  const int h  = b & 31;
  const int kvh = h >> 2;                       // NREP = 4
  const int tid = threadIdx.x;
  const int w = tid >> 6, lane = tid & 63;
  const int lane16 = lane & 15, quad = lane >> 4;
  const float scale = 0.08838834764831845f;     // 1/sqrt(128)
  const int qglob = qt*64 + w*16 + lane16;      // this lane's q column

  const bf16* qrow = qkv + (size_t)qglob * QKVN + h * HD + quad*8;
  bf16x8 qreg[4];
#pragma unroll
  for (int kk = 0; kk < 4; ++kk)
    qreg[kk] = *(const bf16x8*)(qrow + kk*32);

  f32x4 acc_o[8] = {};                          // [jd][reg]: row q=quad*4+reg, col d=jd*16+lane16
  float m_s = -3e38f, l_s = 0.f;                // scalar per lane (column q)

  const bf16* kbase0 = qkv + KOFF + kvh * HD;
  const bf16* vbase0 = vt + (size_t)kvh * HD * SEQ;

  const int L = (qt*64 + 159) / 96;             // ceil((qt+1)*64 / 96) kv tiles
  for (int jj = 0; jj < L; ++jj) {
    const int kv0 = jj * 96;
    __syncthreads();                            // prior iter's ds_reads done before restage
#pragma unroll
    for (int i = 0; i < 6; ++i) {               // 1536 chunks each for K and Vt
      int c = tid + i * 256;
      {
        int kk = c / 384, rem = c - kk*384;     // K: [kk][kvrow][32]
        async_copy16(&Ks[c*8], kbase0 + (size_t)(kv0 + (rem >> 2)) * QKVN + kk*32 + (rem & 3) * 8);
      }
      {
        int kk2 = c >> 9, cp = c & 511;         // Vt: [kk2][d][32kv]
        async_copy16(&Vts[c*8], vbase0 + (size_t)(cp >> 2) * SEQ + kv0 + kk2*32 + (cp & 3) * 8);
      }
    }
    __syncthreads();                            // drains staging

    // S^T = K Q^T : A=K rows (m=kv), B=Q rows (n=q). acc row=kv local, col=q.
    f32x4 accT[6] = {};
#pragma unroll
    for (int kk = 0; kk < 4; ++kk)
#pragma unroll
      for (int jn = 0; jn < 6; ++jn) {
        bf16x8 kf = *(const bf16x8*)&Ks[(kk*96 + jn*16 + lane16)*32 + quad*8];
        accT[jn] = __builtin_amdgcn_mfma_f32_16x16x32_bf16(kf, qreg[kk], accT[jn], 0, 0, 0);
      }

    float s[6][4];
#pragma unroll
    for (int jn = 0; jn < 6; ++jn)
#pragma unroll
      for (int r = 0; r < 4; ++r) {
        float v = accT[jn][r] * scale;
        if ((kv0 + jn*16 + quad*4 + r) > qglob) v = -3e38f;
        s[jn][r] = v;
      }

    float mt = s[0][0];
#pragma unroll
    for (int jn = 0; jn < 6; ++jn)
#pragma unroll
      for (int r = 0; r < 4; ++r) mt = fmaxf(mt, s[jn][r]);
    mt = fmaxf(mt, __shfl_xor(mt, 16));
    mt = fmaxf(mt, __shfl_xor(mt, 32));
    float mnew = fmaxf(m_s, mt);
    float alpha = __expf(m_s - mnew);
    m_s = mnew;
    float rs = 0.f;
#pragma unroll
    for (int jn = 0; jn < 6; ++jn)
#pragma unroll
      for (int r = 0; r < 4; ++r) {
        float p = __expf(s[jn][r] - mnew);
        s[jn][r] = p;
        rs += p;
      }
    rs += __shfl_xor(rs, 16);
    rs += __shfl_xor(rs, 32);
    l_s = l_s * alpha + rs;

    float alpha_row[4];
#pragma unroll
    for (int r = 0; r < 4; ++r)
      alpha_row[r] = __shfl(alpha, quad*4 + r);
#pragma unroll
    for (int jd = 0; jd < 8; ++jd)
#pragma unroll
      for (int r = 0; r < 4; ++r) acc_o[jd][r] *= alpha_row[r];

    uint32_t pk[6][2];
#pragma unroll
    for (int jn = 0; jn < 6; ++jn) {
      pk[jn][0] = pack2bf(s[jn][0], s[jn][1]);
      pk[jn][1] = pack2bf(s[jn][2], s[jn][3]);
    }

    const int src0 = (quad & 1) * 32 + lane16;
    const int src1 = src0 + 16;
    const bool hi = quad >= 2;
#pragma unroll
    for (int kk2 = 0; kk2 < 3; ++kk2) {
      uint32_t v0l = __shfl(pk[2*kk2][0],   src0), v0h = __shfl(pk[2*kk2][1],   src0);
      uint32_t v1l = __shfl(pk[2*kk2][0],   src1), v1h = __shfl(pk[2*kk2][1],   src1);
      uint32_t w0l = __shfl(pk[2*kk2+1][0], src0), w0h = __shfl(pk[2*kk2+1][1], src0);
      uint32_t w1l = __shfl(pk[2*kk2+1][0], src1), w1h = __shfl(pk[2*kk2+1][1], src1);
      union { uint32_t u[4]; bf16x8 v; } af;
      af.u[0] = hi ? w0l : v0l;
      af.u[1] = hi ? w0h : v0h;
      af.u[2] = hi ? w1l : v1l;
      af.u[3] = hi ? w1h : v1h;
#pragma unroll
      for (int jd = 0; jd < 8; ++jd) {
        bf16x8 vf = *(const bf16x8*)&Vts[(kk2*128 + jd*16 + lane16)*32 + quad*8];
        acc_o[jd] = __builtin_amdgcn_mfma_f32_16x16x32_bf16(af.v, vf, acc_o[jd], 0, 0, 0);
      }
    }
  }

  const float inv_l = 1.f / l_s;
  float linv[4];
#pragma unroll
  for (int r = 0; r < 4; ++r)
    linv[r] = __shfl(inv_l, quad*4 + r);

  bf16* obase = out + (size_t)(qt*64 + w*16) * DIM + h * HD;
#pragma unroll
  for (int jd = 0; jd < 8; ++jd)
#pragma unroll
    for (int r = 0; r < 4; ++r)
      obase[(size_t)(quad*4 + r) * DIM + jd*16 + lane16] = (bf16)(acc_o[jd][r] * linv[r]);
}

extern "C" void kernel_launch(void* const* d_in, const int* in_sizes, int n_in,
                              void* d_out, int out_size, void* d_ws, size_t ws_size,
                              hipStream_t stream) {
  const float* x  = (const float*)d_in[0];
  // d_in[1] = cache_kv: dead (start_pos=0, L=SEQ -> keys/values == xk/xv)
  const float* fr = (const float*)d_in[2];
  const float* wq = (const float*)d_in[3];
  const float* wk = (const float*)d_in[4];
  const float* wv = (const float*)d_in[5];
  const float* wo = (const float*)d_in[6];
  // d_in[7] = start_pos = 0
  float* out = (float*)d_out;

  char* ws = (char*)d_ws;
  bf16* xb     = (bf16*)(ws);                    // 2048x4096          16,777,216 B
  bf16* wqkv_t = (bf16*)(ws + 16777216);         // 6144x4096 (N,K)   50,331,648 B
  bf16* wo_t   = (bf16*)(ws + 67108864);         // 4096x4096 (N,K)   33,554,432 B
  bf16* qkv    = (bf16*)(ws + 100663296);        // 2048x6144         25,165,824 B
  bf16* vt     = (bf16*)(ws + 125829120);        // 8x128x2048         4,194,304 B
  bf16* attn   = (bf16*)(ws + 130023424);        // 2048x4096         16,777,216 B
  (void)ws_size; (void)in_sizes; (void)n_in; (void)out_size;

  cast_x_kernel<<<8192, 256, 0, stream>>>(x, xb);
  transpose_cast_kernel<<<dim3(64,64), 256, 0, stream>>>(wq, wqkv_t, DIM, DIM);
  transpose_cast_kernel<<<dim3(16,64), 256, 0, stream>>>(wk, wqkv_t + (size_t)4096*4096, DIM, 1024);
  transpose_cast_kernel<<<dim3(16,64), 256, 0, stream>>>(wv, wqkv_t + (size_t)5120*4096, DIM, 1024);
  transpose_cast_kernel<<<dim3(64,64), 256, 0, stream>>>(wo, wo_t, DIM, DIM);

  gemm256_kernel<0,1,192><<<dim3(32,8), 512, 0, stream>>>(xb, wqkv_t, qkv, SEQ, QKVN, DIM, fr);
  transpose_v_kernel<<<dim3(64,4,8), 256, 0, stream>>>(qkv, vt);
  flash_attn_kernel<<<1024, 256, 0, stream>>>(qkv, vt, attn);
  gemm256_kernel<1,0,128><<<dim3(32,8), 512, 0, stream>>>(attn, wo_t, out, SEQ, DIM, DIM, nullptr);
}

// Round 5
// 588.488 us; speedup vs baseline: 1.0005x; 1.0005x over previous
//
#include <hip/hip_runtime.h>
#include <hip/hip_bf16.h>
#include <stdint.h>

#define SEQ   2048
#define DIM   4096
#define NH    32
#define NKV   8
#define HD    128
#define NREP  4
#define QKVN  6144   /* 4096 q | 1024 k | 1024 v */
#define KOFF  4096
#define VOFF  5120

typedef __bf16 bf16;
typedef __attribute__((ext_vector_type(8))) __bf16 bf16x8;
typedef __attribute__((ext_vector_type(4))) __bf16 bf16x4;
typedef __attribute__((ext_vector_type(4))) float  f32x4;
typedef __attribute__((address_space(1))) void as1_void;
typedef __attribute__((address_space(3))) void as3_void;

__device__ __forceinline__ void async_copy16(void* lds, const void* g) {
  // LDS dest is wave-uniform base + lane*16; global side may be lane-permuted.
  __builtin_amdgcn_global_load_lds((as1_void*)(void*)g, (as3_void*)lds, 16, 0, 0);
}

__device__ __forceinline__ uint32_t pack2bf(float a, float b) {
  union { bf16 h; uint16_t u; } ca, cb;
  ca.h = (bf16)a; cb.h = (bf16)b;
  return (uint32_t)ca.u | ((uint32_t)cb.u << 16);
}

// ---------------- elementwise fp32 -> bf16 cast (x) ----------------
__global__ __launch_bounds__(256) void cast_x_kernel(const float* __restrict__ src,
                                                     bf16* __restrict__ dst) {
  size_t i = ((size_t)blockIdx.x * 256 + threadIdx.x) * 4;
  const float4 v = *(const float4*)(src + i);
  bf16x4 o;
  o[0] = (bf16)v.x; o[1] = (bf16)v.y; o[2] = (bf16)v.z; o[3] = (bf16)v.w;
  *(bf16x4*)(dst + i) = o;
}

// ---------------- tiled transpose-cast: 64x64, float4 loads, bf16x4 stores ----------------
__global__ __launch_bounds__(256) void transpose_cast_kernel(const float* __restrict__ src,
                                                             bf16* __restrict__ dst,
                                                             int R, int C) {
  __shared__ float tile[64][65];
  const int c0 = blockIdx.x * 64, r0 = blockIdx.y * 64;
  const int tx = threadIdx.x & 15, ty = threadIdx.x >> 4;   // 16 x 16
#pragma unroll
  for (int p = 0; p < 4; ++p) {
    float4 v = *(const float4*)&src[(size_t)(r0 + ty + p*16) * C + c0 + tx*4];
    tile[ty + p*16][tx*4+0] = v.x;
    tile[ty + p*16][tx*4+1] = v.y;
    tile[ty + p*16][tx*4+2] = v.z;
    tile[ty + p*16][tx*4+3] = v.w;
  }
  __syncthreads();
  const int k = threadIdx.x & 15;   // dst col quad
  const int g = threadIdx.x >> 4;   // dst row group
#pragma unroll
  for (int p = 0; p < 4; ++p) {
    int X = g + 16*p;               // src col = dst row
    bf16x4 o;
    o[0] = (bf16)tile[4*k+0][X];
    o[1] = (bf16)tile[4*k+1][X];
    o[2] = (bf16)tile[4*k+2][X];
    o[3] = (bf16)tile[4*k+3][X];
    *(bf16x4*)&dst[(size_t)(c0 + X) * R + r0 + 4*k] = o;
  }
}

// ---------------- GEMM v7: round-0 128-row structure + conflict-free LDS + 4 blocks/CU ----
// C(MxN) = A(MxK) * Bt(NxK)^T, bf16 in, fp32 acc. BM=128, BK=64, BN template (96 or 64)
// sized so grid = 1024 blocks = 4/CU for BOTH gemms (round-0's WO ran 2/CU at 470 TF).
// LDS per tile: [row][8 slots x 16B] (128 B rows), slot-XOR: phys slot sl holds k-chunk
// (sl ^ (row&7)). Staging chunk c -> row=c>>3, sl=c&7: 8 consecutive lanes cover one row's
// full 128 B (coalesced), LDS dest lane-linear. Frag read S=((ks*4+quad)^(lane16&7)):
// measured 0 bank conflicts (rounds 2-4) vs 1.26e7 for round-0's [row][32] layout.
// Plain 2-barrier rhythm (__syncthreads drains vmcnt) -- the only schedule verified fast
// on this problem. No setprio (m190: null on lockstep GEMM). 4 waves, wave owns 64xBN/2.
template<int OUT_F32, int ROPE, int BN>
__global__ __launch_bounds__(256) void gemm_bt2_kernel(const bf16* __restrict__ A,
                                                       const bf16* __restrict__ Bt,
                                                       void* __restrict__ Cout,
                                                       int M, int N, int K,
                                                       const float* __restrict__ fr) {
  constexpr int BNF = BN / 32;            // B fragments per wave = B chunks per thread
  __shared__ __align__(16) char ldsA[128 * 128];   // 16 KB
  __shared__ __align__(16) char ldsB[BN * 128];    // 12 KB (96) / 8 KB (64)

  const int tid  = threadIdx.x;
  const int w    = tid >> 6, lane = tid & 63;
  const int lane16 = lane & 15, quad = lane >> 4;
  const int wr = w >> 1, wc = w & 1;               // 2x2 wave grid, wave = 64 x BN/2

  // XCD-aware bijective swizzle (nwg = 1024, %8==0): XCD k gets 2 contiguous M-panels
  const int nwg = gridDim.x * gridDim.y;
  int bid = blockIdx.y * gridDim.x + blockIdx.x;
  bid = (bid & 7) * (nwg >> 3) + (bid >> 3);
  const int bx = bid % gridDim.x, by = bid / gridDim.x;
  const int bm = by * 128, bn = bx * BN;

  f32x4 acc[4][BNF] = {};

  for (int k0 = 0; k0 < K; k0 += 64) {
    __syncthreads();                      // prev iter's LDS reads done before overwrite
#pragma unroll
    for (int i = 0; i < 4; ++i) {         // A: 1024 chunks, 4/thread
      int c = tid + (i << 8);
      int row = c >> 3, sl = c & 7;
      async_copy16(ldsA + c*16,
                   A + (size_t)(bm + row) * K + k0 + ((sl ^ (row & 7)) << 3));
    }
#pragma unroll
    for (int i = 0; i < BNF; ++i) {       // B: BN*8 chunks, BNF/thread
      int c = tid + (i << 8);
      int col = c >> 3, sl = c & 7;
      async_copy16(ldsB + c*16,
                   Bt + (size_t)(bn + col) * K + k0 + ((sl ^ (col & 7)) << 3));
    }
    __syncthreads();                      // implicit vmcnt(0) drain
#pragma unroll
    for (int ks = 0; ks < 2; ++ks) {
      bf16x8 af[4], bfg[BNF];
#pragma unroll
      for (int ii = 0; ii < 4; ++ii) {
        int row_ = wr*64 + ii*16 + lane16;
        int S_ = (ks*4 + quad) ^ (lane16 & 7);
        af[ii] = *(const bf16x8*)(ldsA + row_*128 + S_*16);
      }
#pragma unroll
      for (int jj = 0; jj < BNF; ++jj) {
        int col_ = wc*(BN/2) + jj*16 + lane16;
        int S_ = (ks*4 + quad) ^ (lane16 & 7);
        bfg[jj] = *(const bf16x8*)(ldsB + col_*128 + S_*16);
      }
#pragma unroll
      for (int jj = 0; jj < BNF; ++jj)
#pragma unroll
        for (int ii = 0; ii < 4; ++ii)
          acc[ii][jj] = __builtin_amdgcn_mfma_f32_16x16x32_bf16(af[ii], bfg[jj],
                                                                acc[ii][jj], 0, 0, 0);
    }
  }

  // epilogue: C write (+ optional fused RoPE on cols < 5120)
#pragma unroll
  for (int i = 0; i < 4; ++i)
#pragma unroll
    for (int j = 0; j < BNF; ++j) {
      const int colb = bn + wc*(BN/2) + j*16;
      const bool do_rope = ROPE && colb < 5120;          // wave-uniform per j
      const int p2 = (colb + lane16) & 126;              // 2*p within head
#pragma unroll
      for (int r = 0; r < 4; ++r) {
        size_t row = (size_t)bm + wr*64 + i*16 + quad*4 + r;   // C/D: row=quad*4+reg
        size_t col = (size_t)colb + lane16;                    //      col=lane&15
        float v = acc[i][j][r];
        if (ROPE) {
          float vp = __shfl_xor(v, 1);                   // partner feature value
          if (do_rope) {
            float2 cd = *(const float2*)&fr[row*128 + p2];
            v = (lane16 & 1) ? (vp*cd.y + v*cd.x) : (v*cd.x - vp*cd.y);
          }
        }
        if (OUT_F32) ((float*)Cout)[row * N + col] = v;
        else         ((bf16*)Cout)[row * N + col] = (bf16)v;
      }
    }
}

// ---------------- transpose v slice of qkv -> vt[kv][d][t] ----------------
__global__ __launch_bounds__(256) void transpose_v_kernel(const bf16* __restrict__ qkv,
                                                          bf16* __restrict__ vt) {
  __shared__ bf16 tile[32][33];
  int tt = blockIdx.x * 32;
  int dd = blockIdx.y * 32;
  int kv = blockIdx.z;
  int tx = threadIdx.x & 31, ty = threadIdx.x >> 5;
  const bf16* src = qkv + VOFF + kv * HD;
#pragma unroll
  for (int j = 0; j < 4; ++j)
    tile[ty + j*8][tx] = src[(size_t)(tt + ty + j*8) * QKVN + dd + tx];
  __syncthreads();
  bf16* dst = vt + ((size_t)kv * HD + dd) * SEQ + tt;
#pragma unroll
  for (int j = 0; j < 4; ++j)
    dst[(size_t)(ty + j*8) * SEQ + tx] = tile[tx][ty + j*8];
}

// ---------------- flash attention v3 (unchanged) ----------------
__global__ __launch_bounds__(256, 3) void flash_attn_kernel(const bf16* __restrict__ qkv,
                                                            const bf16* __restrict__ vt,
                                                            bf16* __restrict__ out) {
  __shared__ __align__(16) bf16 Ks[4*96*32];    // [kk=4][kvrow=96][32]   24 KB
  __shared__ __align__(16) bf16 Vts[3*128*32];  // [kk2=3][d=128][32kv]   24 KB
  const int b  = blockIdx.x;                    // 1D, qt-descending for balance
  const int qt = 31 - (b >> 5);
  const int h  = b & 31;
  const int kvh = h >> 2;                       // NREP = 4
  const int tid = threadIdx.x;
  const int w = tid >> 6, lane = tid & 63;
  const int lane16 = lane & 15, quad = lane >> 4;
  const float scale = 0.08838834764831845f;     // 1/sqrt(128)
  const int qglob = qt*64 + w*16 + lane16;      // this lane's q column

  const bf16* qrow = qkv + (size_t)qglob * QKVN + h * HD + quad*8;
  bf16x8 qreg[4];
#pragma unroll
  for (int kk = 0; kk < 4; ++kk)
    qreg[kk] = *(const bf16x8*)(qrow + kk*32);

  f32x4 acc_o[8] = {};                          // [jd][reg]: row q=quad*4+reg, col d=jd*16+lane16
  float m_s = -3e38f, l_s = 0.f;                // scalar per lane (column q)

  const bf16* kbase0 = qkv + KOFF + kvh * HD;
  const bf16* vbase0 = vt + (size_t)kvh * HD * SEQ;

  const int L = (qt*64 + 159) / 96;             // ceil((qt+1)*64 / 96) kv tiles
  for (int jj = 0; jj < L; ++jj) {
    const int kv0 = jj * 96;
    __syncthreads();                            // prior iter's ds_reads done before restage
#pragma unroll
    for (int i = 0; i < 6; ++i) {               // 1536 chunks each for K and Vt
      int c = tid + i * 256;
      {
        int kk = c / 384, rem = c - kk*384;     // K: [kk][kvrow][32]
        async_copy16(&Ks[c*8], kbase0 + (size_t)(kv0 + (rem >> 2)) * QKVN + kk*32 + (rem & 3) * 8);
      }
      {
        int kk2 = c >> 9, cp = c & 511;         // Vt: [kk2][d][32kv]
        async_copy16(&Vts[c*8], vbase0 + (size_t)(cp >> 2) * SEQ + kv0 + kk2*32 + (cp & 3) * 8);
      }
    }
    __syncthreads();                            // drains staging

    // S^T = K Q^T : A=K rows (m=kv), B=Q rows (n=q). acc row=kv local, col=q.
    f32x4 accT[6] = {};
#pragma unroll
    for (int kk = 0; kk < 4; ++kk)
#pragma unroll
      for (int jn = 0; jn < 6; ++jn) {
        bf16x8 kf = *(const bf16x8*)&Ks[(kk*96 + jn*16 + lane16)*32 + quad*8];
        accT[jn] = __builtin_amdgcn_mfma_f32_16x16x32_bf16(kf, qreg[kk], accT[jn], 0, 0, 0);
      }

    float s[6][4];
#pragma unroll
    for (int jn = 0; jn < 6; ++jn)
#pragma unroll
      for (int r = 0; r < 4; ++r) {
        float v = accT[jn][r] * scale;
        if ((kv0 + jn*16 + quad*4 + r) > qglob) v = -3e38f;
        s[jn][r] = v;
      }

    float mt = s[0][0];
#pragma unroll
    for (int jn = 0; jn < 6; ++jn)
#pragma unroll
      for (int r = 0; r < 4; ++r) mt = fmaxf(mt, s[jn][r]);
    mt = fmaxf(mt, __shfl_xor(mt, 16));
    mt = fmaxf(mt, __shfl_xor(mt, 32));
    float mnew = fmaxf(m_s, mt);
    float alpha = __expf(m_s - mnew);
    m_s = mnew;
    float rs = 0.f;
#pragma unroll
    for (int jn = 0; jn < 6; ++jn)
#pragma unroll
      for (int r = 0; r < 4; ++r) {
        float p = __expf(s[jn][r] - mnew);
        s[jn][r] = p;
        rs += p;
      }
    rs += __shfl_xor(rs, 16);
    rs += __shfl_xor(rs, 32);
    l_s = l_s * alpha + rs;

    float alpha_row[4];
#pragma unroll
    for (int r = 0; r < 4; ++r)
      alpha_row[r] = __shfl(alpha, quad*4 + r);
#pragma unroll
    for (int jd = 0; jd < 8; ++jd)
#pragma unroll
      for (int r = 0; r < 4; ++r) acc_o[jd][r] *= alpha_row[r];

    uint32_t pk[6][2];
#pragma unroll
    for (int jn = 0; jn < 6; ++jn) {
      pk[jn][0] = pack2bf(s[jn][0], s[jn][1]);
      pk[jn][1] = pack2bf(s[jn][2], s[jn][3]);
    }

    const int src0 = (quad & 1) * 32 + lane16;
    const int src1 = src0 + 16;
    const bool hi = quad >= 2;
#pragma unroll
    for (int kk2 = 0; kk2 < 3; ++kk2) {
      uint32_t v0l = __shfl(pk[2*kk2][0],   src0), v0h = __shfl(pk[2*kk2][1],   src0);
      uint32_t v1l = __shfl(pk[2*kk2][0],   src1), v1h = __shfl(pk[2*kk2][1],   src1);
      uint32_t w0l = __shfl(pk[2*kk2+1][0], src0), w0h = __shfl(pk[2*kk2+1][1], src0);
      uint32_t w1l = __shfl(pk[2*kk2+1][0], src1), w1h = __shfl(pk[2*kk2+1][1], src1);
      union { uint32_t u[4]; bf16x8 v; } af;
      af.u[0] = hi ? w0l : v0l;
      af.u[1] = hi ? w0h : v0h;
      af.u[2] = hi ? w1l : v1l;
      af.u[3] = hi ? w1h : v1h;
#pragma unroll
      for (int jd = 0; jd < 8; ++jd) {
        bf16x8 vf = *(const bf16x8*)&Vts[(kk2*128 + jd*16 + lane16)*32 + quad*8];
        acc_o[jd] = __builtin_amdgcn_mfma_f32_16x16x32_bf16(af.v, vf, acc_o[jd], 0, 0, 0);
      }
    }
  }

  const float inv_l = 1.f / l_s;
  float linv[4];
#pragma unroll
  for (int r = 0; r < 4; ++r)
    linv[r] = __shfl(inv_l, quad*4 + r);

  bf16* obase = out + (size_t)(qt*64 + w*16) * DIM + h * HD;
#pragma unroll
  for (int jd = 0; jd < 8; ++jd)
#pragma unroll
    for (int r = 0; r < 4; ++r)
      obase[(size_t)(quad*4 + r) * DIM + jd*16 + lane16] = (bf16)(acc_o[jd][r] * linv[r]);
}

extern "C" void kernel_launch(void* const* d_in, const int* in_sizes, int n_in,
                              void* d_out, int out_size, void* d_ws, size_t ws_size,
                              hipStream_t stream) {
  const float* x  = (const float*)d_in[0];
  // d_in[1] = cache_kv: dead (start_pos=0, L=SEQ -> keys/values == xk/xv)
  const float* fr = (const float*)d_in[2];
  const float* wq = (const float*)d_in[3];
  const float* wk = (const float*)d_in[4];
  const float* wv = (const float*)d_in[5];
  const float* wo = (const float*)d_in[6];
  // d_in[7] = start_pos = 0
  float* out = (float*)d_out;

  char* ws = (char*)d_ws;
  bf16* xb     = (bf16*)(ws);                    // 2048x4096          16,777,216 B
  bf16* wqkv_t = (bf16*)(ws + 16777216);         // 6144x4096 (N,K)   50,331,648 B
  bf16* wo_t   = (bf16*)(ws + 67108864);         // 4096x4096 (N,K)   33,554,432 B
  bf16* qkv    = (bf16*)(ws + 100663296);        // 2048x6144         25,165,824 B
  bf16* vt     = (bf16*)(ws + 125829120);        // 8x128x2048         4,194,304 B
  bf16* attn   = (bf16*)(ws + 130023424);        // 2048x4096         16,777,216 B
  (void)ws_size; (void)in_sizes; (void)n_in; (void)out_size;

  cast_x_kernel<<<8192, 256, 0, stream>>>(x, xb);
  transpose_cast_kernel<<<dim3(64,64), 256, 0, stream>>>(wq, wqkv_t, DIM, DIM);
  transpose_cast_kernel<<<dim3(16,64), 256, 0, stream>>>(wk, wqkv_t + (size_t)4096*4096, DIM, 1024);
  transpose_cast_kernel<<<dim3(16,64), 256, 0, stream>>>(wv, wqkv_t + (size_t)5120*4096, DIM, 1024);
  transpose_cast_kernel<<<dim3(64,64), 256, 0, stream>>>(wo, wo_t, DIM, DIM);

  gemm_bt2_kernel<0,1,96><<<dim3(64,16), 256, 0, stream>>>(xb, wqkv_t, qkv, SEQ, QKVN, DIM, fr);
  transpose_v_kernel<<<dim3(64,4,8), 256, 0, stream>>>(qkv, vt);
  flash_attn_kernel<<<1024, 256, 0, stream>>>(qkv, vt, attn);
  gemm_bt2_kernel<1,0,64><<<dim3(64,16), 256, 0, stream>>>(attn, wo_t, out, SEQ, DIM, DIM, nullptr);
}